// Round 2
// baseline (372.559 us; speedup 1.0000x reference)
//
#include <hip/hip_runtime.h>
#include <math.h>

#define NN 100000
#define NE 1600000
#define DD 64
#define ED 16
#define SCAN_B 1024
#define NB1 ((NN + SCAN_B - 1) / SCAN_B)   // 98

// ws layout (4-byte words):
//   xp    [NN*DD]  f32   off 0
//   deg   [NN]     int   off 6,400,000
//   cur   [NN]     int   off 6,500,000
//   bsum  [1024]   int   off 6,600,000
//   bbase [1024]   int   off 6,601,024
//   csr   [NE*2]   int2  off 6,602,048   (byte off 26,408,192 — 8B aligned)
// total ≈ 39.2 MB

// K1: xp[n][o] = x[n]·W_node[o] + b_node[o]; also zeroes deg.
// One wave per 16 nodes; lane o holds W row o (64 VGPR); x row read via
// wave-uniform float4 broadcast loads. Writes xp coalesced. No aliasing.
__global__ __launch_bounds__(256) void proj_kernel(
    const float* __restrict__ x, const float* __restrict__ Wn,
    const float* __restrict__ bn, float* __restrict__ xp,
    int* __restrict__ deg) {
    int tid = threadIdx.x;
    int gi = blockIdx.x * 256 + tid;
    if (gi < NN) deg[gi] = 0;           // grid covers NN (1563*256 = 400128)
    int o = tid & 63;
    int wave = tid >> 6;
    float4 Wr[16];
    const float4* Wn4 = reinterpret_cast<const float4*>(Wn);
#pragma unroll
    for (int k = 0; k < 16; ++k) Wr[k] = Wn4[o * 16 + k];
    float bo = bn[o];
    int n0 = blockIdx.x * 64 + wave * 16;
    for (int j = 0; j < 16; ++j) {
        int n = n0 + j;
        if (n >= NN) break;
        const float4* xr = reinterpret_cast<const float4*>(x + (long)n * DD);
        float acc = bo;
#pragma unroll
        for (int k = 0; k < 16; ++k) {
            float4 a = xr[k];
            acc += a.x * Wr[k].x + a.y * Wr[k].y + a.z * Wr[k].z + a.w * Wr[k].w;
        }
        xp[(long)n * DD + o] = acc;
    }
}

// K2: degree histogram (int atomics, 1.6M over 100k counters)
__global__ __launch_bounds__(256) void count_kernel(const int* __restrict__ ei,
                                                    int* __restrict__ deg) {
    int e = blockIdx.x * 256 + threadIdx.x;
    if (e < NE) atomicAdd(&deg[ei[e]], 1);
}

// S1: per-block inclusive scan (Hillis-Steele) -> local exclusive in cur, block total in bsum
__global__ __launch_bounds__(SCAN_B) void scan1_kernel(const int* __restrict__ deg,
                                                       int* __restrict__ cur,
                                                       int* __restrict__ bsum) {
    __shared__ int s[SCAN_B];
    int t = threadIdx.x;
    int i = blockIdx.x * SCAN_B + t;
    int v = (i < NN) ? deg[i] : 0;
    s[t] = v;
    __syncthreads();
    for (int off = 1; off < SCAN_B; off <<= 1) {
        int add = (t >= off) ? s[t - off] : 0;
        __syncthreads();
        s[t] += add;
        __syncthreads();
    }
    if (i < NN) cur[i] = s[t] - v;
    if (t == SCAN_B - 1) bsum[blockIdx.x] = s[t];
}

// S2: exclusive scan of the NB1 block totals (single block)
__global__ void scan2_kernel(const int* __restrict__ bsum, int* __restrict__ bbase) {
    __shared__ int s[NB1];
    int t = threadIdx.x;
    if (t < NB1) s[t] = bsum[t];
    __syncthreads();
    if (t == 0) {
        int run = 0;
        for (int b = 0; b < NB1; ++b) { int x = s[b]; s[b] = run; run += x; }
    }
    __syncthreads();
    if (t < NB1) bbase[t] = s[t];
}

// S3: add block bases -> cur = global exclusive offsets
__global__ __launch_bounds__(SCAN_B) void scan3_kernel(int* __restrict__ cur,
                                                       const int* __restrict__ bbase) {
    int i = blockIdx.x * SCAN_B + threadIdx.x;
    if (i < NN) cur[i] += bbase[blockIdx.x];
}

// K4: compute gate, claim a CSR slot (int atomic on cursor), write (col, gate).
// After this kernel, cur[n] == offs[n] + deg[n] == row end.
__global__ __launch_bounds__(256) void fill_kernel(
    const int* __restrict__ ei, const float* __restrict__ ef,
    const float* __restrict__ We, const float* __restrict__ be,
    int* __restrict__ cur, int2* __restrict__ csr) {
    int e = blockIdx.x * 256 + threadIdx.x;
    if (e >= NE) return;
    const float4* ef4 = reinterpret_cast<const float4*>(ef + (long)e * ED);
    const float4* We4 = reinterpret_cast<const float4*>(We);
    float4 a0 = ef4[0], a1 = ef4[1], a2 = ef4[2], a3 = ef4[3];
    float4 w0 = We4[0], w1 = We4[1], w2 = We4[2], w3 = We4[3];
    float d = a0.x * w0.x + a0.y * w0.y + a0.z * w0.z + a0.w * w0.w
            + a1.x * w1.x + a1.y * w1.y + a1.z * w1.z + a1.w * w1.w
            + a2.x * w2.x + a2.y * w2.y + a2.z * w2.z + a2.w * w2.w
            + a3.x * w3.x + a3.y * w3.y + a3.z * w3.z + a3.w * w3.w;
    float g = 1.f / (1.f + expf(-(d + be[0])));
    int row = ei[e];
    int col = ei[NE + e];
    int pos = atomicAdd(&cur[row], 1);
    csr[pos] = make_int2(col, __float_as_int(g));
}

// K5: one wave per node, lane = output channel. Walk CSR list, gather xp rows
// (xp table is L2/L3-resident), accumulate in a register, write out once.
__global__ __launch_bounds__(256) void gather_kernel(
    const float* __restrict__ xp, const int* __restrict__ deg,
    const int* __restrict__ cur, const int2* __restrict__ csr,
    float* __restrict__ out) {
    int tid = threadIdx.x;
    int lane = tid & 63;
    int n = blockIdx.x * 4 + (tid >> 6);
    if (n >= NN) return;
    int dn = deg[n];
    int end = cur[n];          // == start + dn after fill
    int start = end - dn;
    float acc = 0.f;
    for (int j = start; j < end; ++j) {
        int2 cg = csr[j];      // wave-uniform address -> single broadcast load
        acc += __int_as_float(cg.y) * xp[(long)cg.x * DD + lane];
    }
    out[(long)n * DD + lane] = acc / fmaxf((float)dn, 1.f);
}

extern "C" void kernel_launch(void* const* d_in, const int* in_sizes, int n_in,
                              void* d_out, int out_size, void* d_ws, size_t ws_size,
                              hipStream_t stream) {
    const float* x  = (const float*)d_in[0];
    const int*   ei = (const int*)d_in[1];   // [2, NE] int32
    const float* ef = (const float*)d_in[2];
    const float* We = (const float*)d_in[3];
    const float* be = (const float*)d_in[4];
    const float* Wn = (const float*)d_in[5];
    const float* bn = (const float*)d_in[6];
    float* out = (float*)d_out;

    float* xp   = (float*)d_ws;
    int*   deg  = (int*)d_ws + 6400000;
    int*   cur  = (int*)d_ws + 6500000;
    int*   bsum = (int*)d_ws + 6600000;
    int*   bbase= (int*)d_ws + 6601024;
    int2*  csr  = (int2*)((int*)d_ws + 6602048);

    proj_kernel<<<(NN + 63) / 64, 256, 0, stream>>>(x, Wn, bn, xp, deg);
    count_kernel<<<(NE + 255) / 256, 256, 0, stream>>>(ei, deg);
    scan1_kernel<<<NB1, SCAN_B, 0, stream>>>(deg, cur, bsum);
    scan2_kernel<<<1, 128, 0, stream>>>(bsum, bbase);
    scan3_kernel<<<NB1, SCAN_B, 0, stream>>>(cur, bbase);
    fill_kernel<<<(NE + 255) / 256, 256, 0, stream>>>(ei, ef, We, be, cur, csr);
    gather_kernel<<<(NN + 3) / 4, 256, 0, stream>>>(xp, deg, cur, csr, out);
}

// Round 3
// 298.320 us; speedup vs baseline: 1.2489x; 1.2489x over previous
//
#include <hip/hip_runtime.h>
#include <math.h>

#define NN 100000
#define NE 1600000
#define DD 64
#define ED 16
#define SCAN_B 1024
#define NB1 ((NN + SCAN_B - 1) / SCAN_B)   // 98

// ws layout (4-byte words):
//   xp    [NN*DD]  f32   off 0
//   deg   [NN]     int   off 6,400,000
//   cur   [NN]     int   off 6,500,000
//   bsum  [1024]   int   off 6,600,000
//   bbase [1024]   int   off 6,601,024
//   csr   [NE*2]   int2  off 6,602,048   (byte off 26,408,192 — 8B aligned)

// K1: xp[n][o] = x[n]·W_node[o] + b_node[o]; also zeroes deg.
__global__ __launch_bounds__(256) void proj_kernel(
    const float* __restrict__ x, const float* __restrict__ Wn,
    const float* __restrict__ bn, float* __restrict__ xp,
    int* __restrict__ deg) {
    int tid = threadIdx.x;
    int gi = blockIdx.x * 256 + tid;
    if (gi < NN) deg[gi] = 0;           // grid covers NN (1563*256 = 400128)
    int o = tid & 63;
    int wave = tid >> 6;
    float4 Wr[16];
    const float4* Wn4 = reinterpret_cast<const float4*>(Wn);
#pragma unroll
    for (int k = 0; k < 16; ++k) Wr[k] = Wn4[o * 16 + k];
    float bo = bn[o];
    int n0 = blockIdx.x * 64 + wave * 16;
    for (int j = 0; j < 16; ++j) {
        int n = n0 + j;
        if (n >= NN) break;
        const float4* xr = reinterpret_cast<const float4*>(x + (long)n * DD);
        float acc = bo;
#pragma unroll
        for (int k = 0; k < 16; ++k) {
            float4 a = xr[k];
            acc += a.x * Wr[k].x + a.y * Wr[k].y + a.z * Wr[k].z + a.w * Wr[k].w;
        }
        xp[(long)n * DD + o] = acc;
    }
}

// K2: degree histogram, 4 edges/thread via int4
__global__ __launch_bounds__(256) void count_kernel(const int4* __restrict__ ei4,
                                                    int* __restrict__ deg) {
    int i = blockIdx.x * 256 + threadIdx.x;
    if (i < NE / 4) {
        int4 r = ei4[i];
        atomicAdd(&deg[r.x], 1);
        atomicAdd(&deg[r.y], 1);
        atomicAdd(&deg[r.z], 1);
        atomicAdd(&deg[r.w], 1);
    }
}

// S1: per-block scan -> local exclusive offsets in cur, block total in bsum
__global__ __launch_bounds__(SCAN_B) void scan1_kernel(const int* __restrict__ deg,
                                                       int* __restrict__ cur,
                                                       int* __restrict__ bsum) {
    __shared__ int s[SCAN_B];
    int t = threadIdx.x;
    int i = blockIdx.x * SCAN_B + t;
    int v = (i < NN) ? deg[i] : 0;
    s[t] = v;
    __syncthreads();
    for (int off = 1; off < SCAN_B; off <<= 1) {
        int add = (t >= off) ? s[t - off] : 0;
        __syncthreads();
        s[t] += add;
        __syncthreads();
    }
    if (i < NN) cur[i] = s[t] - v;
    if (t == SCAN_B - 1) bsum[blockIdx.x] = s[t];
}

// S2: exclusive scan of block totals (single block)
__global__ void scan2_kernel(const int* __restrict__ bsum, int* __restrict__ bbase) {
    __shared__ int s[NB1];
    int t = threadIdx.x;
    if (t < NB1) s[t] = bsum[t];
    __syncthreads();
    if (t == 0) {
        int run = 0;
        for (int b = 0; b < NB1; ++b) { int x = s[b]; s[b] = run; run += x; }
    }
    __syncthreads();
    if (t < NB1) bbase[t] = s[t];
}

// K4: gate + slot claim. cur holds LOCAL offsets; global pos = local + bbase[row>>10].
__global__ __launch_bounds__(256) void fill_kernel(
    const int* __restrict__ ei, const float* __restrict__ ef,
    const float* __restrict__ We, const float* __restrict__ be,
    int* __restrict__ cur, const int* __restrict__ bbase,
    int2* __restrict__ csr) {
    int e = blockIdx.x * 256 + threadIdx.x;
    if (e >= NE) return;
    const float4* ef4 = reinterpret_cast<const float4*>(ef + (long)e * ED);
    const float4* We4 = reinterpret_cast<const float4*>(We);
    float4 a0 = ef4[0], a1 = ef4[1], a2 = ef4[2], a3 = ef4[3];
    float4 w0 = We4[0], w1 = We4[1], w2 = We4[2], w3 = We4[3];
    float d = a0.x * w0.x + a0.y * w0.y + a0.z * w0.z + a0.w * w0.w
            + a1.x * w1.x + a1.y * w1.y + a1.z * w1.z + a1.w * w1.w
            + a2.x * w2.x + a2.y * w2.y + a2.z * w2.z + a2.w * w2.w
            + a3.x * w3.x + a3.y * w3.y + a3.z * w3.z + a3.w * w3.w;
    float g = 1.f / (1.f + expf(-(d + be[0])));
    int row = ei[e];
    int col = ei[NE + e];
    int pos = atomicAdd(&cur[row], 1) + bbase[row >> 10];
    csr[pos] = make_int2(col, __float_as_int(g));
}

// K5: one wave per node, lane = channel. 8-wide unrolled CSR walk with
// predicated (clamped) tail so all loads issue in parallel — no serial chain.
__global__ __launch_bounds__(256) void gather_kernel(
    const float* __restrict__ xp, const int* __restrict__ deg,
    const int* __restrict__ cur, const int* __restrict__ bbase,
    const int2* __restrict__ csr, float* __restrict__ out) {
    int tid = threadIdx.x;
    int lane = tid & 63;
    int n = blockIdx.x * 4 + (tid >> 6);
    if (n >= NN) return;
    int dn = deg[n];
    int end = cur[n] + bbase[n >> 10];   // after fill, cur[n] = local_off + dn
    int start = end - dn;
    float a0 = 0.f, a1 = 0.f, a2 = 0.f, a3 = 0.f;
    for (int j = start; j < end; j += 8) {
        int2 c0 = csr[min(j + 0, end - 1)];
        int2 c1 = csr[min(j + 1, end - 1)];
        int2 c2 = csr[min(j + 2, end - 1)];
        int2 c3 = csr[min(j + 3, end - 1)];
        int2 c4 = csr[min(j + 4, end - 1)];
        int2 c5 = csr[min(j + 5, end - 1)];
        int2 c6 = csr[min(j + 6, end - 1)];
        int2 c7 = csr[min(j + 7, end - 1)];
        float v0 = xp[(long)c0.x * DD + lane];
        float v1 = xp[(long)c1.x * DD + lane];
        float v2 = xp[(long)c2.x * DD + lane];
        float v3 = xp[(long)c3.x * DD + lane];
        float v4 = xp[(long)c4.x * DD + lane];
        float v5 = xp[(long)c5.x * DD + lane];
        float v6 = xp[(long)c6.x * DD + lane];
        float v7 = xp[(long)c7.x * DD + lane];
        float g0 = (j + 0 < end) ? __int_as_float(c0.y) : 0.f;
        float g1 = (j + 1 < end) ? __int_as_float(c1.y) : 0.f;
        float g2 = (j + 2 < end) ? __int_as_float(c2.y) : 0.f;
        float g3 = (j + 3 < end) ? __int_as_float(c3.y) : 0.f;
        float g4 = (j + 4 < end) ? __int_as_float(c4.y) : 0.f;
        float g5 = (j + 5 < end) ? __int_as_float(c5.y) : 0.f;
        float g6 = (j + 6 < end) ? __int_as_float(c6.y) : 0.f;
        float g7 = (j + 7 < end) ? __int_as_float(c7.y) : 0.f;
        a0 += g0 * v0; a1 += g1 * v1; a2 += g2 * v2; a3 += g3 * v3;
        a0 += g4 * v4; a1 += g5 * v5; a2 += g6 * v6; a3 += g7 * v7;
    }
    float acc = (a0 + a1) + (a2 + a3);
    out[(long)n * DD + lane] = acc / fmaxf((float)dn, 1.f);
}

extern "C" void kernel_launch(void* const* d_in, const int* in_sizes, int n_in,
                              void* d_out, int out_size, void* d_ws, size_t ws_size,
                              hipStream_t stream) {
    const float* x  = (const float*)d_in[0];
    const int*   ei = (const int*)d_in[1];   // [2, NE] int32
    const float* ef = (const float*)d_in[2];
    const float* We = (const float*)d_in[3];
    const float* be = (const float*)d_in[4];
    const float* Wn = (const float*)d_in[5];
    const float* bn = (const float*)d_in[6];
    float* out = (float*)d_out;

    float* xp   = (float*)d_ws;
    int*   deg  = (int*)d_ws + 6400000;
    int*   cur  = (int*)d_ws + 6500000;
    int*   bsum = (int*)d_ws + 6600000;
    int*   bbase= (int*)d_ws + 6601024;
    int2*  csr  = (int2*)((int*)d_ws + 6602048);

    proj_kernel<<<(NN + 63) / 64, 256, 0, stream>>>(x, Wn, bn, xp, deg);
    count_kernel<<<(NE / 4 + 255) / 256, 256, 0, stream>>>((const int4*)ei, deg);
    scan1_kernel<<<NB1, SCAN_B, 0, stream>>>(deg, cur, bsum);
    scan2_kernel<<<1, 128, 0, stream>>>(bsum, bbase);
    fill_kernel<<<(NE + 255) / 256, 256, 0, stream>>>(ei, ef, We, be, cur, bbase, csr);
    gather_kernel<<<(NN + 3) / 4, 256, 0, stream>>>(xp, deg, cur, bbase, csr, out);
}

// Round 4
// 261.969 us; speedup vs baseline: 1.4222x; 1.1388x over previous
//
#include <hip/hip_runtime.h>
#include <math.h>

#define NN 100000
#define NE 1600000
#define DD 64
#define ED 16
#define SCAN_B 1024
#define NB1 ((NN + SCAN_B - 1) / SCAN_B)   // 98

// ws layout (4-byte words):
//   xp    [NN*DD]  f32   off 0
//   deg   [NN]     int   off 6,400,000
//   cur   [NN]     int   off 6,500,000
//   bsum  [1024]   int   off 6,600,000
//   bbase [1024]   int   off 6,601,024
//   csr   [NE*2]   int2  off 6,602,048   (byte off 26,408,192 — 8B aligned)

// K1: xp[n][o] = x[n]·W_node[o] + b_node[o]; also zeroes deg.
// LDS-tiled: 64 x-rows staged coalesced into 16 KB LDS; wave w computes
// nodes w*16..w*16+15 from LDS broadcast reads against register-held W row.
__global__ __launch_bounds__(256) void proj_kernel(
    const float* __restrict__ x, const float* __restrict__ Wn,
    const float* __restrict__ bn, float* __restrict__ xp,
    int* __restrict__ deg) {
    __shared__ float4 xs[64 * 16];   // 64 nodes x 16 float4 = 16 KB
    int tid = threadIdx.x;
    int gi = blockIdx.x * 256 + tid;
    if (gi < NN) deg[gi] = 0;        // grid covers NN (1563*256 = 400128)
    int o = tid & 63;
    int wave = tid >> 6;
    float4 Wr[16];
    const float4* Wn4 = reinterpret_cast<const float4*>(Wn);
#pragma unroll
    for (int k = 0; k < 16; ++k) Wr[k] = Wn4[o * 16 + k];
    float bo = bn[o];
    int n0 = blockIdx.x * 64;
    // cooperative coalesced stage: 1024 float4s, 4 per thread
    const float4* x4 = reinterpret_cast<const float4*>(x);
    long base = (long)n0 * 16;
    long limit = (long)NN * 16;
#pragma unroll
    for (int i = 0; i < 4; ++i) {
        long idx = base + tid + 256 * i;
        xs[tid + 256 * i] = (idx < limit) ? x4[idx] : make_float4(0.f, 0.f, 0.f, 0.f);
    }
    __syncthreads();
#pragma unroll
    for (int j = 0; j < 16; ++j) {
        int ln = wave * 16 + j;
        int n = n0 + ln;
        if (n >= NN) break;          // wave-uniform
        float acc = bo;
#pragma unroll
        for (int k = 0; k < 16; ++k) {
            float4 a = xs[ln * 16 + k];   // wave-uniform LDS addr -> broadcast
            acc += a.x * Wr[k].x + a.y * Wr[k].y + a.z * Wr[k].z + a.w * Wr[k].w;
        }
        xp[(long)n * DD + o] = acc;  // coalesced
    }
}

// K2: degree histogram, 4 edges/thread via int4
__global__ __launch_bounds__(256) void count_kernel(const int4* __restrict__ ei4,
                                                    int* __restrict__ deg) {
    int i = blockIdx.x * 256 + threadIdx.x;
    if (i < NE / 4) {
        int4 r = ei4[i];
        atomicAdd(&deg[r.x], 1);
        atomicAdd(&deg[r.y], 1);
        atomicAdd(&deg[r.z], 1);
        atomicAdd(&deg[r.w], 1);
    }
}

// S1: per-block scan -> local exclusive offsets in cur, block total in bsum
__global__ __launch_bounds__(SCAN_B) void scan1_kernel(const int* __restrict__ deg,
                                                       int* __restrict__ cur,
                                                       int* __restrict__ bsum) {
    __shared__ int s[SCAN_B];
    int t = threadIdx.x;
    int i = blockIdx.x * SCAN_B + t;
    int v = (i < NN) ? deg[i] : 0;
    s[t] = v;
    __syncthreads();
    for (int off = 1; off < SCAN_B; off <<= 1) {
        int add = (t >= off) ? s[t - off] : 0;
        __syncthreads();
        s[t] += add;
        __syncthreads();
    }
    if (i < NN) cur[i] = s[t] - v;
    if (t == SCAN_B - 1) bsum[blockIdx.x] = s[t];
}

// S2: exclusive scan of block totals (single block)
__global__ void scan2_kernel(const int* __restrict__ bsum, int* __restrict__ bbase) {
    __shared__ int s[NB1];
    int t = threadIdx.x;
    if (t < NB1) s[t] = bsum[t];
    __syncthreads();
    if (t == 0) {
        int run = 0;
        for (int b = 0; b < NB1; ++b) { int x = s[b]; s[b] = run; run += x; }
    }
    __syncthreads();
    if (t < NB1) bbase[t] = s[t];
}

// K4: gate + slot claim. cur holds LOCAL offsets; global pos = local + bbase[row>>10].
__global__ __launch_bounds__(256) void fill_kernel(
    const int* __restrict__ ei, const float* __restrict__ ef,
    const float* __restrict__ We, const float* __restrict__ be,
    int* __restrict__ cur, const int* __restrict__ bbase,
    int2* __restrict__ csr) {
    int e = blockIdx.x * 256 + threadIdx.x;
    if (e >= NE) return;
    const float4* ef4 = reinterpret_cast<const float4*>(ef + (long)e * ED);
    const float4* We4 = reinterpret_cast<const float4*>(We);
    float4 a0 = ef4[0], a1 = ef4[1], a2 = ef4[2], a3 = ef4[3];
    float4 w0 = We4[0], w1 = We4[1], w2 = We4[2], w3 = We4[3];
    float d = a0.x * w0.x + a0.y * w0.y + a0.z * w0.z + a0.w * w0.w
            + a1.x * w1.x + a1.y * w1.y + a1.z * w1.z + a1.w * w1.w
            + a2.x * w2.x + a2.y * w2.y + a2.z * w2.z + a2.w * w2.w
            + a3.x * w3.x + a3.y * w3.y + a3.z * w3.z + a3.w * w3.w;
    float g = 1.f / (1.f + expf(-(d + be[0])));
    int row = ei[e];
    int col = ei[NE + e];
    int pos = atomicAdd(&cur[row], 1) + bbase[row >> 10];
    csr[pos] = make_int2(col, __float_as_int(g));
}

// K5: one wave per node, lane = channel. 8-wide unrolled CSR walk with
// predicated (clamped) tail so all loads issue in parallel — no serial chain.
__global__ __launch_bounds__(256) void gather_kernel(
    const float* __restrict__ xp, const int* __restrict__ deg,
    const int* __restrict__ cur, const int* __restrict__ bbase,
    const int2* __restrict__ csr, float* __restrict__ out) {
    int tid = threadIdx.x;
    int lane = tid & 63;
    int n = blockIdx.x * 4 + (tid >> 6);
    if (n >= NN) return;
    int dn = deg[n];
    int end = cur[n] + bbase[n >> 10];   // after fill, cur[n] = local_off + dn
    int start = end - dn;
    float a0 = 0.f, a1 = 0.f, a2 = 0.f, a3 = 0.f;
    for (int j = start; j < end; j += 8) {
        int2 c0 = csr[min(j + 0, end - 1)];
        int2 c1 = csr[min(j + 1, end - 1)];
        int2 c2 = csr[min(j + 2, end - 1)];
        int2 c3 = csr[min(j + 3, end - 1)];
        int2 c4 = csr[min(j + 4, end - 1)];
        int2 c5 = csr[min(j + 5, end - 1)];
        int2 c6 = csr[min(j + 6, end - 1)];
        int2 c7 = csr[min(j + 7, end - 1)];
        float v0 = xp[(long)c0.x * DD + lane];
        float v1 = xp[(long)c1.x * DD + lane];
        float v2 = xp[(long)c2.x * DD + lane];
        float v3 = xp[(long)c3.x * DD + lane];
        float v4 = xp[(long)c4.x * DD + lane];
        float v5 = xp[(long)c5.x * DD + lane];
        float v6 = xp[(long)c6.x * DD + lane];
        float v7 = xp[(long)c7.x * DD + lane];
        float g0 = (j + 0 < end) ? __int_as_float(c0.y) : 0.f;
        float g1 = (j + 1 < end) ? __int_as_float(c1.y) : 0.f;
        float g2 = (j + 2 < end) ? __int_as_float(c2.y) : 0.f;
        float g3 = (j + 3 < end) ? __int_as_float(c3.y) : 0.f;
        float g4 = (j + 4 < end) ? __int_as_float(c4.y) : 0.f;
        float g5 = (j + 5 < end) ? __int_as_float(c5.y) : 0.f;
        float g6 = (j + 6 < end) ? __int_as_float(c6.y) : 0.f;
        float g7 = (j + 7 < end) ? __int_as_float(c7.y) : 0.f;
        a0 += g0 * v0; a1 += g1 * v1; a2 += g2 * v2; a3 += g3 * v3;
        a0 += g4 * v4; a1 += g5 * v5; a2 += g6 * v6; a3 += g7 * v7;
    }
    float acc = (a0 + a1) + (a2 + a3);
    out[(long)n * DD + lane] = acc / fmaxf((float)dn, 1.f);
}

extern "C" void kernel_launch(void* const* d_in, const int* in_sizes, int n_in,
                              void* d_out, int out_size, void* d_ws, size_t ws_size,
                              hipStream_t stream) {
    const float* x  = (const float*)d_in[0];
    const int*   ei = (const int*)d_in[1];   // [2, NE] int32
    const float* ef = (const float*)d_in[2];
    const float* We = (const float*)d_in[3];
    const float* be = (const float*)d_in[4];
    const float* Wn = (const float*)d_in[5];
    const float* bn = (const float*)d_in[6];
    float* out = (float*)d_out;

    float* xp   = (float*)d_ws;
    int*   deg  = (int*)d_ws + 6400000;
    int*   cur  = (int*)d_ws + 6500000;
    int*   bsum = (int*)d_ws + 6600000;
    int*   bbase= (int*)d_ws + 6601024;
    int2*  csr  = (int2*)((int*)d_ws + 6602048);

    proj_kernel<<<(NN + 63) / 64, 256, 0, stream>>>(x, Wn, bn, xp, deg);
    count_kernel<<<(NE / 4 + 255) / 256, 256, 0, stream>>>((const int4*)ei, deg);
    scan1_kernel<<<NB1, SCAN_B, 0, stream>>>(deg, cur, bsum);
    scan2_kernel<<<1, 128, 0, stream>>>(bsum, bbase);
    fill_kernel<<<(NE + 255) / 256, 256, 0, stream>>>(ei, ef, We, be, cur, bbase, csr);
    gather_kernel<<<(NN + 3) / 4, 256, 0, stream>>>(xp, deg, cur, bbase, csr, out);
}

// Round 5
// 249.559 us; speedup vs baseline: 1.4929x; 1.0497x over previous
//
#include <hip/hip_runtime.h>
#include <math.h>

#define NN 100000
#define NE 1600000
#define DD 64
#define ED 16
#define SCAN_B 1024
#define NB1 ((NN + SCAN_B - 1) / SCAN_B)   // 98

// ws layout (4-byte words):
//   xpb   [NN*DD]  bf16(ushort)  word off 0          (3,200,000 words)
//   deg   [NN]     int           word off 3,200,000
//   cur   [NN]     int           word off 3,300,000
//   bsum  [1024]   int           word off 3,400,000
//   bbase [1024]   int           word off 3,401,024
//   csr   [<=3.1M] int2          word off 3,402,048  (byte 13,608,192, 16B aligned)
// total ≈ 38.4 MB

__device__ __forceinline__ unsigned short f2bf(float f) {
    unsigned int b = __float_as_uint(f);
    unsigned int r = (b + 0x7FFFu + ((b >> 16) & 1u)) >> 16;   // RNE
    return (unsigned short)r;
}
__device__ __forceinline__ float bf2f(unsigned short u) {
    return __uint_as_float(((unsigned int)u) << 16);
}

// K1: xp[n][o] = bf16(x[n]·W_node[o] + b_node[o]); also zeroes deg.
// 64 x-rows staged coalesced into 16 KB LDS; wave w computes nodes
// w*16..w*16+15 from LDS broadcast reads against its register-held W row.
__global__ __launch_bounds__(256) void proj_kernel(
    const float* __restrict__ x, const float* __restrict__ Wn,
    const float* __restrict__ bn, unsigned short* __restrict__ xpb,
    int* __restrict__ deg) {
    __shared__ float4 xs[64 * 16];   // 16 KB
    int tid = threadIdx.x;
    int gi = blockIdx.x * 256 + tid;
    if (gi < NN) deg[gi] = 0;        // grid covers NN (1563*256 = 400128)
    int o = tid & 63;
    int wave = tid >> 6;
    float4 Wr[16];
    const float4* Wn4 = reinterpret_cast<const float4*>(Wn);
#pragma unroll
    for (int k = 0; k < 16; ++k) Wr[k] = Wn4[o * 16 + k];
    float bo = bn[o];
    int n0 = blockIdx.x * 64;
    const float4* x4 = reinterpret_cast<const float4*>(x);
    long base = (long)n0 * 16;
    long limit = (long)NN * 16;
#pragma unroll
    for (int i = 0; i < 4; ++i) {
        long idx = base + tid + 256 * i;
        xs[tid + 256 * i] = (idx < limit) ? x4[idx] : make_float4(0.f, 0.f, 0.f, 0.f);
    }
    __syncthreads();
#pragma unroll
    for (int j = 0; j < 16; ++j) {
        int ln = wave * 16 + j;
        int n = n0 + ln;
        if (n >= NN) break;          // wave-uniform
        float acc = bo;
#pragma unroll
        for (int k = 0; k < 16; ++k) {
            float4 a = xs[ln * 16 + k];   // wave-uniform LDS addr -> broadcast
            acc += a.x * Wr[k].x + a.y * Wr[k].y + a.z * Wr[k].z + a.w * Wr[k].w;
        }
        xpb[(long)n * DD + o] = f2bf(acc);
    }
}

// K2: degree histogram, 4 edges/thread via int4
__global__ __launch_bounds__(256) void count_kernel(const int4* __restrict__ ei4,
                                                    int* __restrict__ deg) {
    int i = blockIdx.x * 256 + threadIdx.x;
    if (i < NE / 4) {
        int4 r = ei4[i];
        atomicAdd(&deg[r.x], 1);
        atomicAdd(&deg[r.y], 1);
        atomicAdd(&deg[r.z], 1);
        atomicAdd(&deg[r.w], 1);
    }
}

// S1: per-block scan of PADDED degrees -> local exclusive offsets in cur,
// block total in bsum. pdeg = round-up-16(deg).
__global__ __launch_bounds__(SCAN_B) void scan1_kernel(const int* __restrict__ deg,
                                                       int* __restrict__ cur,
                                                       int* __restrict__ bsum) {
    __shared__ int s[SCAN_B];
    int t = threadIdx.x;
    int i = blockIdx.x * SCAN_B + t;
    int v = (i < NN) ? ((deg[i] + 15) & ~15) : 0;
    s[t] = v;
    __syncthreads();
    for (int off = 1; off < SCAN_B; off <<= 1) {
        int add = (t >= off) ? s[t - off] : 0;
        __syncthreads();
        s[t] += add;
        __syncthreads();
    }
    if (i < NN) cur[i] = s[t] - v;
    if (t == SCAN_B - 1) bsum[blockIdx.x] = s[t];
}

// S2: exclusive scan of block totals (single block)
__global__ void scan2_kernel(const int* __restrict__ bsum, int* __restrict__ bbase) {
    __shared__ int s[NB1];
    int t = threadIdx.x;
    if (t < NB1) s[t] = bsum[t];
    __syncthreads();
    if (t == 0) {
        int run = 0;
        for (int b = 0; b < NB1; ++b) { int x = s[b]; s[b] = run; run += x; }
    }
    __syncthreads();
    if (t < NB1) bbase[t] = s[t];
}

// K3b: zero-fill the pad slots [start+deg, start+pdeg) of every row.
// Runs BEFORE fill (cur still holds local exclusive starts).
__global__ __launch_bounds__(256) void pad_kernel(
    const int* __restrict__ deg, const int* __restrict__ cur,
    const int* __restrict__ bbase, int2* __restrict__ csr) {
    int n = blockIdx.x * 256 + threadIdx.x;
    if (n >= NN) return;
    int d = deg[n];
    int pd = (d + 15) & ~15;
    int start = cur[n] + bbase[n >> 10];
    for (int j = start + d; j < start + pd; ++j) csr[j] = make_int2(0, 0);
}

// K4: gate + slot claim. cur holds LOCAL padded offsets; pos = local + bbase.
__global__ __launch_bounds__(256) void fill_kernel(
    const int* __restrict__ ei, const float* __restrict__ ef,
    const float* __restrict__ We, const float* __restrict__ be,
    int* __restrict__ cur, const int* __restrict__ bbase,
    int2* __restrict__ csr) {
    int e = blockIdx.x * 256 + threadIdx.x;
    if (e >= NE) return;
    const float4* ef4 = reinterpret_cast<const float4*>(ef + (long)e * ED);
    const float4* We4 = reinterpret_cast<const float4*>(We);
    float4 a0 = ef4[0], a1 = ef4[1], a2 = ef4[2], a3 = ef4[3];
    float4 w0 = We4[0], w1 = We4[1], w2 = We4[2], w3 = We4[3];
    float d = a0.x * w0.x + a0.y * w0.y + a0.z * w0.z + a0.w * w0.w
            + a1.x * w1.x + a1.y * w1.y + a1.z * w1.z + a1.w * w1.w
            + a2.x * w2.x + a2.y * w2.y + a2.z * w2.z + a2.w * w2.w
            + a3.x * w3.x + a3.y * w3.y + a3.z * w3.z + a3.w * w3.w;
    float g = 1.f / (1.f + expf(-(d + be[0])));
    int row = ei[e];
    int col = ei[NE + e];
    int pos = atomicAdd(&cur[row], 1) + bbase[row >> 10];
    csr[pos] = make_int2(col, __float_as_int(g));
}

// K5: one wave per node, lane = channel. Branchless 16-wide trips over the
// padded row: 8 wave-uniform int4 csr loads + 16 bf16 gathers + 16 FMA.
// Pad entries have gate=0, col=0 (xp row 0 stays L1-hot -> ~free).
__global__ __launch_bounds__(256) void gather_kernel(
    const unsigned short* __restrict__ xpb, const int* __restrict__ deg,
    const int* __restrict__ cur, const int* __restrict__ bbase,
    const int2* __restrict__ csr, float* __restrict__ out) {
    int tid = threadIdx.x;
    int lane = tid & 63;
    int n = blockIdx.x * 4 + (tid >> 6);
    if (n >= NN) return;
    int dn = deg[n];
    int start = cur[n] + bbase[n >> 10] - dn;   // after fill: cur = local_start + deg
    int pdn = (dn + 15) & ~15;
    float a0 = 0.f, a1 = 0.f, a2 = 0.f, a3 = 0.f;
    for (int j = start; j < start + pdn; j += 16) {
        const int4* c4 = reinterpret_cast<const int4*>(csr + j);  // 128B aligned
        int4 e0 = c4[0], e1 = c4[1], e2 = c4[2], e3 = c4[3];
        int4 e4 = c4[4], e5 = c4[5], e6 = c4[6], e7 = c4[7];
        float v0 = bf2f(xpb[(long)e0.x * DD + lane]);
        float v1 = bf2f(xpb[(long)e0.z * DD + lane]);
        float v2 = bf2f(xpb[(long)e1.x * DD + lane]);
        float v3 = bf2f(xpb[(long)e1.z * DD + lane]);
        float v4 = bf2f(xpb[(long)e2.x * DD + lane]);
        float v5 = bf2f(xpb[(long)e2.z * DD + lane]);
        float v6 = bf2f(xpb[(long)e3.x * DD + lane]);
        float v7 = bf2f(xpb[(long)e3.z * DD + lane]);
        float v8 = bf2f(xpb[(long)e4.x * DD + lane]);
        float v9 = bf2f(xpb[(long)e4.z * DD + lane]);
        float va = bf2f(xpb[(long)e5.x * DD + lane]);
        float vb = bf2f(xpb[(long)e5.z * DD + lane]);
        float vc = bf2f(xpb[(long)e6.x * DD + lane]);
        float vd = bf2f(xpb[(long)e6.z * DD + lane]);
        float ve = bf2f(xpb[(long)e7.x * DD + lane]);
        float vf = bf2f(xpb[(long)e7.z * DD + lane]);
        a0 += __int_as_float(e0.y) * v0; a1 += __int_as_float(e0.w) * v1;
        a2 += __int_as_float(e1.y) * v2; a3 += __int_as_float(e1.w) * v3;
        a0 += __int_as_float(e2.y) * v4; a1 += __int_as_float(e2.w) * v5;
        a2 += __int_as_float(e3.y) * v6; a3 += __int_as_float(e3.w) * v7;
        a0 += __int_as_float(e4.y) * v8; a1 += __int_as_float(e4.w) * v9;
        a2 += __int_as_float(e5.y) * va; a3 += __int_as_float(e5.w) * vb;
        a0 += __int_as_float(e6.y) * vc; a1 += __int_as_float(e6.w) * vd;
        a2 += __int_as_float(e7.y) * ve; a3 += __int_as_float(e7.w) * vf;
    }
    float acc = (a0 + a1) + (a2 + a3);
    out[(long)n * DD + lane] = acc / fmaxf((float)dn, 1.f);
}

extern "C" void kernel_launch(void* const* d_in, const int* in_sizes, int n_in,
                              void* d_out, int out_size, void* d_ws, size_t ws_size,
                              hipStream_t stream) {
    const float* x  = (const float*)d_in[0];
    const int*   ei = (const int*)d_in[1];   // [2, NE] int32
    const float* ef = (const float*)d_in[2];
    const float* We = (const float*)d_in[3];
    const float* be = (const float*)d_in[4];
    const float* Wn = (const float*)d_in[5];
    const float* bn = (const float*)d_in[6];
    float* out = (float*)d_out;

    unsigned short* xpb = (unsigned short*)d_ws;
    int*  deg   = (int*)d_ws + 3200000;
    int*  cur   = (int*)d_ws + 3300000;
    int*  bsum  = (int*)d_ws + 3400000;
    int*  bbase = (int*)d_ws + 3401024;
    int2* csr   = (int2*)((int*)d_ws + 3402048);

    proj_kernel<<<(NN + 63) / 64, 256, 0, stream>>>(x, Wn, bn, xpb, deg);
    count_kernel<<<(NE / 4 + 255) / 256, 256, 0, stream>>>((const int4*)ei, deg);
    scan1_kernel<<<NB1, SCAN_B, 0, stream>>>(deg, cur, bsum);
    scan2_kernel<<<1, 128, 0, stream>>>(bsum, bbase);
    pad_kernel<<<(NN + 255) / 256, 256, 0, stream>>>(deg, cur, bbase, csr);
    fill_kernel<<<(NE + 255) / 256, 256, 0, stream>>>(ei, ef, We, be, cur, bbase, csr);
    gather_kernel<<<(NN + 3) / 4, 256, 0, stream>>>(xpb, deg, cur, bbase, csr, out);
}